// Round 7
// baseline (48.607 us; speedup 1.0000x reference)
//
#include <hip/hip_runtime.h>
#include <math.h>

#define M_CB 8
#define K_CB 1024
#define D_CB 128
#define HW   1024
#define NB   4
#define HALF_LOG_2PI 0.9189385332046727f
#define EPS_S 1e-5f
#define LOG2E 1.4426950408889634f
#define LN2   0.6931471805599453f

typedef float f32x4 __attribute__((ext_vector_type(4)));
typedef short s16x8 __attribute__((ext_vector_type(8)));

__device__ __forceinline__ void gl2lds16(const void* g, void* l) {
    __builtin_amdgcn_global_load_lds(
        (const __attribute__((address_space(1))) void*)g,
        (__attribute__((address_space(3))) void*)l, 16, 0, 0);
}

__device__ __forceinline__ short f2bf(float f) {   // RNE fp32 -> bf16 bits
    unsigned u = __builtin_bit_cast(unsigned, f);
    u += 0x7fffu + ((u >> 16) & 1u);
    return (short)(u >> 16);
}

__device__ __forceinline__ f32x4 splat4(float v) { return (f32x4){v, v, v, v}; }

// ws float offsets
#define WS_PART  16                      // 1024 partials
#define WS_A     4096                    // A2l [8][1024]
#define WS_C0    (WS_A + 8192)           // c0l [8][1024]
#define WS_MU_F  (WS_C0 + 8192)          // frag-major bf16 mus, 2 MB

// ---- kernel 1: mus -> bf16 FRAG-MAJOR + per-k constants (log2 domain) ----------
__global__ __launch_bounds__(256) void vq_convert(
    const float* __restrict__ mus, const float* __restrict__ scales,
    const float* __restrict__ logpy, ushort* __restrict__ wmu,
    float* __restrict__ A2l, float* __restrict__ c0l)
{
    const int t  = blockIdx.x * 256 + threadIdx.x;
    const int db = t & 15;
    const int k  = (t >> 4) & (K_CB - 1);
    const int m  = t >> 14;
    const float* row = mus + ((size_t)m * K_CB + k) * D_CB;
    const float4 v0 = *reinterpret_cast<const float4*>(row + db * 8);
    const float4 v1 = *reinterpret_cast<const float4*>(row + db * 8 + 4);
    s16x8 o;
    o[0] = f2bf(v0.x); o[1] = f2bf(v0.y); o[2] = f2bf(v0.z); o[3] = f2bf(v0.w);
    o[4] = f2bf(v1.x); o[5] = f2bf(v1.y); o[6] = f2bf(v1.z); o[7] = f2bf(v1.w);
    const int kt = k >> 4, dc = db >> 2, lane = (db & 3) * 16 + (k & 15);
    reinterpret_cast<s16x8*>(wmu)[(size_t)(m * 64 + kt) * 256 + dc * 64 + lane] = o;

    float ssq = v0.x*v0.x + v0.y*v0.y + v0.z*v0.z + v0.w*v0.w
              + v1.x*v1.x + v1.y*v1.y + v1.z*v1.z + v1.w*v1.w;
    #pragma unroll
    for (int o2 = 8; o2 >= 1; o2 >>= 1) ssq += __shfl_xor(ssq, o2, 64);
    if (db == 0) {
        const float s = fmaxf(scales[m * K_CB + k], EPS_S);
        const float A = 0.5f / (s * s);
        const float lpy = logpy[m * K_CB + k];
        A2l[m * K_CB + k] = 2.f * A * LOG2E;
        c0l[m * K_CB + k] = (fmaf(-(float)D_CB, logf(s) + HALF_LOG_2PI, lpy) - A * ssq) * LOG2E;
    }
}

// ---- kernel 2: MFMA dist + branchless packed softmax/KL/argmax -----------------
// grid (128, 8): 128 tiles of 32 px, m. Block: 4 waves, each = k-quarter x 32 px.
__global__ __launch_bounds__(256, 4) void vq_main(
    const float* __restrict__ x, const ushort* __restrict__ wmu,
    const float* __restrict__ mus, const float* __restrict__ A2l,
    const float* __restrict__ c0l, const float* __restrict__ logpy,
    float* __restrict__ out, float* __restrict__ partial)
{
    __shared__ __align__(16) float As[1024];
    __shared__ __align__(16) float Cs[1024];
    __shared__ __align__(16) float Ps[1024];
    __shared__ float mM[3][32], mS[3][32], mU[3][32], mV[3][32];
    __shared__ int   mBI[3][32], sidx[32];

    const int tid = threadIdx.x;
    const int w   = tid >> 6;           // wave 0..3 = k-quarter
    const int l   = tid & 63;
    const int g   = l >> 4;             // k-subset in wave
    const int n   = l & 15;             // pixel within group
    const int bx  = blockIdx.x;         // 0..127 (32-px tiles)
    const int m   = blockIdx.y;
    const int img = bx >> 5;
    const int hw0 = (bx & 31) * 32;
    const size_t xbase = (size_t)img * (M_CB * D_CB * HW) + (size_t)m * (D_CB * HW) + hw0;

    // ---- stage full per-k consts (3 x 4KB) ----
    gl2lds16((const char*)(A2l   + m * K_CB) + tid * 16, (char*)As + tid * 16);
    gl2lds16((const char*)(c0l   + m * K_CB) + tid * 16, (char*)Cs + tid * 16);
    gl2lds16((const char*)(logpy + m * K_CB) + tid * 16, (char*)Ps + tid * 16);

    // ---- x fragments + ||x||^2 for 2 pixel groups, straight from global ----
    const float* xpx = x + xbase + n;
    float xs0 = 0.f, xs1 = 0.f;
    s16x8 xf0[4], xf1[4];
    #pragma unroll
    for (int c = 0; c < 4; ++c) {
        #pragma unroll
        for (int j = 0; j < 8; ++j) {
            const size_t off = (size_t)(c * 32 + g * 8 + j) * HW;
            const float v0 = xpx[off];
            const float v1 = xpx[off + 16];
            xs0 = fmaf(v0, v0, xs0); xf0[c][j] = f2bf(v0);
            xs1 = fmaf(v1, v1, xs1); xf1[c][j] = f2bf(v1);
        }
    }
    xs0 += __shfl_xor(xs0, 16, 64); xs0 += __shfl_xor(xs0, 32, 64);
    xs1 += __shfl_xor(xs1, 16, 64); xs1 += __shfl_xor(xs1, 32, 64);
    const float nxsh0 = -0.5f * xs0;     // baked into MFMA C-init
    const float nxsh1 = -0.5f * xs1;
    __syncthreads();                     // consts staged

    // ---- packed softmax/KL state (f32x4 lanes = 4 independent chains) ----
    float M0 = -1e30f, M1 = -1e30f;
    f32x4 S0v = splat4(0.f), U0v = splat4(0.f), V0v = splat4(0.f);
    f32x4 S1v = splat4(0.f), U1v = splat4(0.f), V1v = splat4(0.f);
    int BI0 = 0, BI1 = 0;

    const s16x8* __restrict__ wf = reinterpret_cast<const s16x8*>(wmu)
                                 + (size_t)(m * 64 + w * 16) * 256 + l;

    s16x8 a0, a1, a2, a3;
    { const s16x8* fb = wf; a0 = fb[0]; a1 = fb[64]; a2 = fb[128]; a3 = fb[192]; }

    #pragma unroll 2
    for (int t = 0; t < 16; ++t) {
        s16x8 b0, b1, b2, b3;
        if (t < 15) {                    // 1-deep register prefetch of next k-tile
            const s16x8* fb = wf + (t + 1) * 256;
            b0 = fb[0]; b1 = fb[64]; b2 = fb[128]; b3 = fb[192];
        }
        f32x4 p = splat4(nxsh0), q = splat4(nxsh1);   // C-init = -||x||^2/2
        p = __builtin_amdgcn_mfma_f32_16x16x32_bf16(a0, xf0[0], p, 0, 0, 0);
        q = __builtin_amdgcn_mfma_f32_16x16x32_bf16(a0, xf1[0], q, 0, 0, 0);
        p = __builtin_amdgcn_mfma_f32_16x16x32_bf16(a1, xf0[1], p, 0, 0, 0);
        q = __builtin_amdgcn_mfma_f32_16x16x32_bf16(a1, xf1[1], q, 0, 0, 0);
        p = __builtin_amdgcn_mfma_f32_16x16x32_bf16(a2, xf0[2], p, 0, 0, 0);
        q = __builtin_amdgcn_mfma_f32_16x16x32_bf16(a2, xf1[2], q, 0, 0, 0);
        p = __builtin_amdgcn_mfma_f32_16x16x32_bf16(a3, xf0[3], p, 0, 0, 0);
        q = __builtin_amdgcn_mfma_f32_16x16x32_bf16(a3, xf1[3], q, 0, 0, 0);

        const int k0 = (w * 16 + t) * 16 + g * 4;     // global k of lane's 4 logits
        const f32x4 A4 = *(const f32x4*)(As + k0);
        const f32x4 C4 = *(const f32x4*)(Cs + k0);
        const f32x4 P4 = *(const f32x4*)(Ps + k0);

        auto epi = [&](const f32x4& acc, float& M, f32x4& Sv, f32x4& Uv, f32x4& Vv,
                       int& BI) {
            const f32x4 L = __builtin_elementwise_fma(A4, acc, C4);   // logits (log2)
            const float tmax = fmaxf(fmaxf(L[0], L[1]), fmaxf(L[2], L[3]));
            // ---- argmax (per-tile; lowest r preferred on in-tile tie) ----
            const bool ch = tmax > M;
            const int ridx = (L[0] == tmax) ? 0 : (L[1] == tmax) ? 1
                           : (L[2] == tmax) ? 2 : 3;
            BI = ch ? (k0 + ridx) : BI;
            // ---- unconditional rescale (sc==1.0 exactly when max unchanged) ----
            const float Mn = ch ? tmax : M;
            const float dm = M - Mn;                  // <= 0
            const float sc = exp2f(dm);
            const f32x4 sc4 = splat4(sc);
            Uv = (Uv + splat4(dm) * Sv) * sc4;
            Sv = Sv * sc4;
            Vv = Vv * sc4;
            M = Mn;
            // ---- packed accumulate ----
            const f32x4 dv = L - splat4(Mn);
            f32x4 ev;
            ev[0] = exp2f(dv[0]); ev[1] = exp2f(dv[1]);
            ev[2] = exp2f(dv[2]); ev[3] = exp2f(dv[3]);
            Sv += ev;
            Uv = __builtin_elementwise_fma(ev, dv, Uv);
            Vv = __builtin_elementwise_fma(ev, P4, Vv);
        };
        epi(p, M0, S0v, U0v, V0v, BI0);
        epi(q, M1, S1v, U1v, V1v, BI1);

        a0 = b0; a1 = b1; a2 = b2; a3 = b3;
    }

    // ---- horizontal sum of packed state (all components share M) ----
    float S0 = (S0v[0] + S0v[1]) + (S0v[2] + S0v[3]);
    float U0 = (U0v[0] + U0v[1]) + (U0v[2] + U0v[3]);
    float V0 = (V0v[0] + V0v[1]) + (V0v[2] + V0v[3]);
    float S1 = (S1v[0] + S1v[1]) + (S1v[2] + S1v[3]);
    float U1 = (U1v[0] + U1v[1]) + (U1v[2] + U1v[3]);
    float V1 = (V1v[0] + V1v[1]) + (V1v[2] + V1v[3]);

    // ---- intra-wave butterfly merge of 4 k-subsets (g bits), both px groups ----
    auto mergeShfl = [&](float& M2, float& S, float& U2, float& V, int& BI) {
        #pragma unroll
        for (int off = 16; off <= 32; off <<= 1) {
            const float Mb  = __shfl_xor(M2, off, 64);
            const float Sb  = __shfl_xor(S,  off, 64);
            const float Ub  = __shfl_xor(U2, off, 64);
            const float Vb  = __shfl_xor(V,  off, 64);
            const int   BIb = __shfl_xor(BI, off, 64);
            const bool tb = (Mb > M2) || (Mb == M2 && BIb < BI);   // argmax first
            BI = tb ? BIb : BI;
            const float Mc = fmaxf(M2, Mb);
            const float sa = exp2f(M2 - Mc), sb = exp2f(Mb - Mc);
            const float Sn = S * sa + Sb * sb;
            U2 = fmaf(M2 - Mc, S, U2) * sa + fmaf(Mb - Mc, Sb, Ub) * sb;
            V  = V * sa + Vb * sb;
            S  = Sn; M2 = Mc;
        }
    };
    mergeShfl(M0, S0, U0, V0, BI0);
    mergeShfl(M1, S1, U1, V1, BI1);

    // ---- cross-wave merge (4 k-quarters) via LDS ----
    if (w > 0 && l < 16) {
        mM[w-1][n]    = M0;  mS[w-1][n]    = S0;  mU[w-1][n]    = U0;
        mV[w-1][n]    = V0;  mBI[w-1][n]   = BI0;
        mM[w-1][16+n] = M1;  mS[w-1][16+n] = S1;  mU[w-1][16+n] = U1;
        mV[w-1][16+n] = V1;  mBI[w-1][16+n] = BI1;
    }
    __syncthreads();
    if (w == 0 && l < 16) {
        auto mergeL = [&](int px, float& M2, float& S, float& U2, float& V, int& BI) {
            #pragma unroll
            for (int i = 0; i < 3; ++i) {
                const float Mb = mM[i][px], Sb = mS[i][px];
                const float Ub = mU[i][px], Vb = mV[i][px];
                const int BIb = mBI[i][px];
                const bool tb = (Mb > M2) || (Mb == M2 && BIb < BI);
                BI = tb ? BIb : BI;
                const float Mc = fmaxf(M2, Mb);
                const float sa = exp2f(M2 - Mc), sb = exp2f(Mb - Mc);
                const float Sn = S * sa + Sb * sb;
                U2 = fmaf(M2 - Mc, S, U2) * sa + fmaf(Mb - Mc, Sb, Ub) * sb;
                V  = V * sa + Vb * sb;
                S  = Sn; M2 = Mc;
            }
        };
        mergeL(n,      M0, S0, U0, V0, BI0);
        mergeL(16 + n, M1, S1, U1, V1, BI1);
        sidx[n]      = BI0;
        sidx[16 + n] = BI1;
        float kl = (LN2 * U0 - V0) / S0 - logf(S0)
                 + (LN2 * U1 - V1) / S1 - logf(S1);   // +lse[m] correction in vq_final
        #pragma unroll
        for (int o = 8; o >= 1; o >>= 1) kl += __shfl_xor(kl, o, 64);
        if (l == 0) partial[m * 128 + bx] = kl;
    }
    __syncthreads();

    // ---- sample: direct gather + coalesced store (32 px x 16 d per thread) ----
    {
        const int px = tid & 31, dgrp = tid >> 5;     // dgrp 0..7, 16 d each
        const float* mrow = mus + ((size_t)m * K_CB + sidx[px]) * D_CB + dgrp * 16;
        float* ob = out + xbase + (size_t)dgrp * 16 * HW + px;
        #pragma unroll
        for (int i = 0; i < 4; ++i) {
            const float4 v = reinterpret_cast<const float4*>(mrow)[i];
            ob[(size_t)(i * 4 + 0) * HW] = v.x;
            ob[(size_t)(i * 4 + 1) * HW] = v.y;
            ob[(size_t)(i * 4 + 2) * HW] = v.z;
            ob[(size_t)(i * 4 + 3) * HW] = v.w;
        }
    }
}

// ---- kernel 3: lse correction + final KL reduce -------------------------------
__global__ __launch_bounds__(256) void vq_final(const float* __restrict__ logpy,
                                                const float* __restrict__ partial,
                                                float* __restrict__ out)
{
    __shared__ float lses[8];
    __shared__ float wred[4];
    const int tid = threadIdx.x;
    const int mm = tid >> 5, lane = tid & 31;

    float M = -1e30f, S = 0.f;
    #pragma unroll 4
    for (int i = 0; i < 32; ++i) {
        const float v = logpy[mm * K_CB + i * 32 + lane];
        const float Mn = fmaxf(M, v);
        S = S * expf(M - Mn) + expf(v - Mn);
        M = Mn;
    }
    #pragma unroll
    for (int off = 16; off >= 1; off >>= 1) {
        const float Mb = __shfl_xor(M, off, 32);
        const float Sb = __shfl_xor(S, off, 32);
        const float Mn = fmaxf(M, Mb);
        S = S * expf(M - Mn) + Sb * expf(Mb - Mn);
        M = Mn;
    }
    if (lane == 0) lses[mm] = M + logf(S);

    float v = partial[tid] + partial[tid + 256] + partial[tid + 512] + partial[tid + 768];
    #pragma unroll
    for (int o = 32; o >= 1; o >>= 1) v += __shfl_xor(v, o, 64);
    if ((tid & 63) == 0) wred[tid >> 6] = v;
    __syncthreads();
    if (tid == 0) {
        const float ksum = wred[0] + wred[1] + wred[2] + wred[3];
        const float lsesum = lses[0] + lses[1] + lses[2] + lses[3]
                           + lses[4] + lses[5] + lses[6] + lses[7];
        out[(size_t)NB * M_CB * D_CB * HW]     = (ksum + 4096.f * lsesum) * 0.25f;
        out[(size_t)NB * M_CB * D_CB * HW + 1] = 0.f;
    }
}

extern "C" void kernel_launch(void* const* d_in, const int* in_sizes, int n_in,
                              void* d_out, int out_size, void* d_ws, size_t ws_size,
                              hipStream_t stream)
{
    const float* x      = (const float*)d_in[0];
    const float* mus    = (const float*)d_in[1];
    const float* scales = (const float*)d_in[2];
    const float* logpy  = (const float*)d_in[3];
    float* out = (float*)d_out;
    float* ws  = (float*)d_ws;

    float*  partial = ws + WS_PART;
    float*  A2l     = ws + WS_A;
    float*  c0l     = ws + WS_C0;
    ushort* wmu     = (ushort*)(ws + WS_MU_F);

    vq_convert<<<512,          256, 0, stream>>>(mus, scales, logpy, wmu, A2l, c0l);
    vq_main   <<<dim3(128, 8), 256, 0, stream>>>(x, wmu, mus, A2l, c0l, logpy, out, partial);
    vq_final  <<<1,            256, 0, stream>>>(logpy, partial, out);
}

// Round 8
// 43.490 us; speedup vs baseline: 1.1177x; 1.1177x over previous
//
#include <hip/hip_runtime.h>
#include <math.h>

#define M_CB 8
#define K_CB 1024
#define D_CB 128
#define HW   1024
#define NB   4
#define HALF_LOG_2PI 0.9189385332046727f
#define EPS_S 1e-5f
#define LOG2E 1.4426950408889634f
#define LN2   0.6931471805599453f
#define DEFER_THR 12.0f

typedef float f32x4 __attribute__((ext_vector_type(4)));
typedef short s16x8 __attribute__((ext_vector_type(8)));

__device__ __forceinline__ void gl2lds16(const void* g, void* l) {
    __builtin_amdgcn_global_load_lds(
        (const __attribute__((address_space(1))) void*)g,
        (__attribute__((address_space(3))) void*)l, 16, 0, 0);
}

__device__ __forceinline__ short f2bf(float f) {   // RNE fp32 -> bf16 bits
    unsigned u = __builtin_bit_cast(unsigned, f);
    u += 0x7fffu + ((u >> 16) & 1u);
    return (short)(u >> 16);
}

__device__ __forceinline__ f32x4 splat4(float v) { return (f32x4){v, v, v, v}; }

// ws float offsets
#define WS_PART  16                      // 1024 partials
#define WS_A     4096                    // A2l [8][1024]
#define WS_C0    (WS_A + 8192)           // c0l [8][1024]
#define WS_MU_F  (WS_C0 + 8192)          // frag-major bf16 mus, 2 MB

// ---- kernel 1: mus -> bf16 FRAG-MAJOR + per-k constants (log2 domain) ----------
__global__ __launch_bounds__(256) void vq_convert(
    const float* __restrict__ mus, const float* __restrict__ scales,
    const float* __restrict__ logpy, ushort* __restrict__ wmu,
    float* __restrict__ A2l, float* __restrict__ c0l)
{
    const int t  = blockIdx.x * 256 + threadIdx.x;
    const int db = t & 15;
    const int k  = (t >> 4) & (K_CB - 1);
    const int m  = t >> 14;
    const float* row = mus + ((size_t)m * K_CB + k) * D_CB;
    const float4 v0 = *reinterpret_cast<const float4*>(row + db * 8);
    const float4 v1 = *reinterpret_cast<const float4*>(row + db * 8 + 4);
    s16x8 o;
    o[0] = f2bf(v0.x); o[1] = f2bf(v0.y); o[2] = f2bf(v0.z); o[3] = f2bf(v0.w);
    o[4] = f2bf(v1.x); o[5] = f2bf(v1.y); o[6] = f2bf(v1.z); o[7] = f2bf(v1.w);
    const int kt = k >> 4, dc = db >> 2, lane = (db & 3) * 16 + (k & 15);
    reinterpret_cast<s16x8*>(wmu)[(size_t)(m * 64 + kt) * 256 + dc * 64 + lane] = o;

    float ssq = v0.x*v0.x + v0.y*v0.y + v0.z*v0.z + v0.w*v0.w
              + v1.x*v1.x + v1.y*v1.y + v1.z*v1.z + v1.w*v1.w;
    #pragma unroll
    for (int o2 = 8; o2 >= 1; o2 >>= 1) ssq += __shfl_xor(ssq, o2, 64);
    if (db == 0) {
        const float s = fmaxf(scales[m * K_CB + k], EPS_S);
        const float A = 0.5f / (s * s);
        const float lpy = logpy[m * K_CB + k];
        A2l[m * K_CB + k] = 2.f * A * LOG2E;
        c0l[m * K_CB + k] = (fmaf(-(float)D_CB, logf(s) + HALF_LOG_2PI, lpy) - A * ssq) * LOG2E;
    }
}

// ---- kernel 2: MFMA dist + per-tile deferred softmax/KL/argmax -----------------
// grid (128, 8): 128 tiles of 32 px, m. Block: 4 waves, each = k-quarter x 32 px.
__global__ __launch_bounds__(256, 4) void vq_main(
    const float* __restrict__ x, const ushort* __restrict__ wmu,
    const float* __restrict__ mus, const float* __restrict__ A2l,
    const float* __restrict__ c0l, const float* __restrict__ logpy,
    float* __restrict__ out, float* __restrict__ partial)
{
    __shared__ __align__(16) float As[1024];
    __shared__ __align__(16) float Cs[1024];
    __shared__ __align__(16) float Ps[1024];
    __shared__ float mM[3][32], mS[3][32], mU[3][32], mV[3][32], mBL[3][32];
    __shared__ int   mBI[3][32], sidx[32];

    const int tid = threadIdx.x;
    const int w   = tid >> 6;           // wave 0..3 = k-quarter
    const int l   = tid & 63;
    const int g   = l >> 4;             // k-subset in wave
    const int n   = l & 15;             // pixel within group
    const int bx  = blockIdx.x;         // 0..127 (32-px tiles)
    const int m   = blockIdx.y;
    const int img = bx >> 5;
    const int hw0 = (bx & 31) * 32;
    const size_t xbase = (size_t)img * (M_CB * D_CB * HW) + (size_t)m * (D_CB * HW) + hw0;

    // ---- stage full per-k consts (3 x 4KB) ----
    gl2lds16((const char*)(A2l   + m * K_CB) + tid * 16, (char*)As + tid * 16);
    gl2lds16((const char*)(c0l   + m * K_CB) + tid * 16, (char*)Cs + tid * 16);
    gl2lds16((const char*)(logpy + m * K_CB) + tid * 16, (char*)Ps + tid * 16);

    // ---- x fragments + ||x||^2 for 2 pixel groups, straight from global ----
    const float* xpx = x + xbase + n;
    float xs0 = 0.f, xs1 = 0.f;
    s16x8 xf0[4], xf1[4];
    #pragma unroll
    for (int c = 0; c < 4; ++c) {
        #pragma unroll
        for (int j = 0; j < 8; ++j) {
            const size_t off = (size_t)(c * 32 + g * 8 + j) * HW;
            const float v0 = xpx[off];
            const float v1 = xpx[off + 16];
            xs0 = fmaf(v0, v0, xs0); xf0[c][j] = f2bf(v0);
            xs1 = fmaf(v1, v1, xs1); xf1[c][j] = f2bf(v1);
        }
    }
    xs0 += __shfl_xor(xs0, 16, 64); xs0 += __shfl_xor(xs0, 32, 64);
    xs1 += __shfl_xor(xs1, 16, 64); xs1 += __shfl_xor(xs1, 32, 64);
    const float nxsh0 = -0.5f * xs0;     // folded into MFMA C-init
    const float nxsh1 = -0.5f * xs1;
    __syncthreads();                     // consts staged

    // ---- deferred-max state (log2 domain), scalar per pixel group ----
    float M0 = -1e30f, S0 = 0.f, U0 = 0.f, V0 = 0.f, BL0 = -1e30f;
    float M1 = -1e30f, S1 = 0.f, U1 = 0.f, V1 = 0.f, BL1 = -1e30f;
    int BI0 = 0, BI1 = 0;

    const s16x8* __restrict__ wf = reinterpret_cast<const s16x8*>(wmu)
                                 + (size_t)(m * 64 + w * 16) * 256 + l;

    s16x8 a0, a1, a2, a3;
    { const s16x8* fb = wf; a0 = fb[0]; a1 = fb[64]; a2 = fb[128]; a3 = fb[192]; }

    #pragma unroll 2
    for (int t = 0; t < 16; ++t) {
        s16x8 b0, b1, b2, b3;
        if (t < 15) {                    // 1-deep register prefetch of next k-tile
            const s16x8* fb = wf + (t + 1) * 256;
            b0 = fb[0]; b1 = fb[64]; b2 = fb[128]; b3 = fb[192];
        }
        f32x4 p = splat4(nxsh0), q = splat4(nxsh1);   // C-init = -||x||^2/2
        p = __builtin_amdgcn_mfma_f32_16x16x32_bf16(a0, xf0[0], p, 0, 0, 0);
        q = __builtin_amdgcn_mfma_f32_16x16x32_bf16(a0, xf1[0], q, 0, 0, 0);
        p = __builtin_amdgcn_mfma_f32_16x16x32_bf16(a1, xf0[1], p, 0, 0, 0);
        q = __builtin_amdgcn_mfma_f32_16x16x32_bf16(a1, xf1[1], q, 0, 0, 0);
        p = __builtin_amdgcn_mfma_f32_16x16x32_bf16(a2, xf0[2], p, 0, 0, 0);
        q = __builtin_amdgcn_mfma_f32_16x16x32_bf16(a2, xf1[2], q, 0, 0, 0);
        p = __builtin_amdgcn_mfma_f32_16x16x32_bf16(a3, xf0[3], p, 0, 0, 0);
        q = __builtin_amdgcn_mfma_f32_16x16x32_bf16(a3, xf1[3], q, 0, 0, 0);

        const int k0 = (w * 16 + t) * 16 + g * 4;     // global k of lane's 4 logits
        const f32x4 A4 = *(const f32x4*)(As + k0);
        const f32x4 C4 = *(const f32x4*)(Cs + k0);
        const f32x4 P4 = *(const f32x4*)(Ps + k0);

        auto epi = [&](const f32x4& acc, float& M, float& S, float& U, float& V,
                       float& BL, int& BI) {
            const f32x4 L = __builtin_elementwise_fma(A4, acc, C4);  // logits (log2)
            const float tmax = fmaxf(fmaxf(L[0], L[1]), fmaxf(L[2], L[3]));
            // rare: rescale reference when tile max exceeds M by > THR
            if (__builtin_expect(__any(tmax - M > DEFER_THR), 0)) {
                if (tmax - M > DEFER_THR) {
                    const float gg = M - tmax;            // < 0
                    const float sc = exp2f(gg);
                    U = fmaf(gg, S, U) * sc;
                    S *= sc; V *= sc;
                    M = tmax;
                }
            }
            // per-tile argmax (predicated, ~8 ops)
            const bool ch = tmax > BL;
            const int ridx = (L[0] == tmax) ? 0 : (L[1] == tmax) ? 1
                           : (L[2] == tmax) ? 2 : 3;
            BI = ch ? (k0 + ridx) : BI;
            BL = ch ? tmax : BL;
            // common path: 5 ops/logit, no max bookkeeping
            #pragma unroll
            for (int r = 0; r < 4; ++r) {
                const float d = L[r] - M;
                const float e = exp2f(d);
                S += e;
                U = fmaf(e, d, U);
                V = fmaf(e, P4[r], V);
            }
        };
        epi(p, M0, S0, U0, V0, BL0, BI0);
        epi(q, M1, S1, U1, V1, BL1, BI1);

        a0 = b0; a1 = b1; a2 = b2; a3 = b3;
    }

    // ---- intra-wave butterfly merge of 4 k-subsets (g bits), both px groups ----
    auto mergeShfl = [&](float& M2, float& S, float& U2, float& V, float& BL, int& BI) {
        #pragma unroll
        for (int off = 16; off <= 32; off <<= 1) {
            const float Mb  = __shfl_xor(M2, off, 64);
            const float Sb  = __shfl_xor(S,  off, 64);
            const float Ub  = __shfl_xor(U2, off, 64);
            const float Vb  = __shfl_xor(V,  off, 64);
            const float BLb = __shfl_xor(BL, off, 64);
            const int   BIb = __shfl_xor(BI, off, 64);
            const float Mc = fmaxf(M2, Mb);
            const float sa = exp2f(M2 - Mc), sb = exp2f(Mb - Mc);
            const float Sn = S * sa + Sb * sb;
            U2 = fmaf(M2 - Mc, S, U2) * sa + fmaf(Mb - Mc, Sb, Ub) * sb;
            V  = V * sa + Vb * sb;
            S  = Sn; M2 = Mc;
            const bool tb = (BLb > BL) || (BLb == BL && BIb < BI);
            BI = tb ? BIb : BI;
            BL = fmaxf(BL, BLb);
        }
    };
    mergeShfl(M0, S0, U0, V0, BL0, BI0);
    mergeShfl(M1, S1, U1, V1, BL1, BI1);

    // ---- cross-wave merge (4 k-quarters) via LDS ----
    if (w > 0 && l < 16) {
        mM[w-1][n]      = M0;  mS[w-1][n]      = S0;  mU[w-1][n]      = U0;
        mV[w-1][n]      = V0;  mBL[w-1][n]     = BL0; mBI[w-1][n]     = BI0;
        mM[w-1][16+n]   = M1;  mS[w-1][16+n]   = S1;  mU[w-1][16+n]   = U1;
        mV[w-1][16+n]   = V1;  mBL[w-1][16+n]  = BL1; mBI[w-1][16+n]  = BI1;
    }
    __syncthreads();
    if (w == 0 && l < 16) {
        auto mergeL = [&](int px, float& M2, float& S, float& U2, float& V,
                          float& BL, int& BI) {
            #pragma unroll
            for (int i = 0; i < 3; ++i) {
                const float Mb = mM[i][px], Sb = mS[i][px], Ub = mU[i][px], Vb = mV[i][px];
                const float BLb = mBL[i][px]; const int BIb = mBI[i][px];
                const float Mc = fmaxf(M2, Mb);
                const float sa = exp2f(M2 - Mc), sb = exp2f(Mb - Mc);
                const float Sn = S * sa + Sb * sb;
                U2 = fmaf(M2 - Mc, S, U2) * sa + fmaf(Mb - Mc, Sb, Ub) * sb;
                V  = V * sa + Vb * sb;
                S  = Sn; M2 = Mc;
                const bool tb = (BLb > BL) || (BLb == BL && BIb < BI);
                BI = tb ? BIb : BI;
                BL = fmaxf(BL, BLb);
            }
        };
        mergeL(n,      M0, S0, U0, V0, BL0, BI0);
        mergeL(16 + n, M1, S1, U1, V1, BL1, BI1);
        sidx[n]      = BI0;
        sidx[16 + n] = BI1;
        float kl = (LN2 * U0 - V0) / S0 - logf(S0)
                 + (LN2 * U1 - V1) / S1 - logf(S1);   // +lse[m] correction in vq_final
        #pragma unroll
        for (int o = 8; o >= 1; o >>= 1) kl += __shfl_xor(kl, o, 64);
        if (l == 0) partial[m * 128 + bx] = kl;
    }
    __syncthreads();

    // ---- sample: direct gather + coalesced store (32 px x 16 d per thread) ----
    {
        const int px = tid & 31, dgrp = tid >> 5;     // dgrp 0..7, 16 d each
        const float* mrow = mus + ((size_t)m * K_CB + sidx[px]) * D_CB + dgrp * 16;
        float* ob = out + xbase + (size_t)dgrp * 16 * HW + px;
        #pragma unroll
        for (int i = 0; i < 4; ++i) {
            const float4 v = reinterpret_cast<const float4*>(mrow)[i];
            ob[(size_t)(i * 4 + 0) * HW] = v.x;
            ob[(size_t)(i * 4 + 1) * HW] = v.y;
            ob[(size_t)(i * 4 + 2) * HW] = v.z;
            ob[(size_t)(i * 4 + 3) * HW] = v.w;
        }
    }
}

// ---- kernel 3: lse correction + final KL reduce -------------------------------
__global__ __launch_bounds__(256) void vq_final(const float* __restrict__ logpy,
                                                const float* __restrict__ partial,
                                                float* __restrict__ out)
{
    __shared__ float lses[8];
    __shared__ float wred[4];
    const int tid = threadIdx.x;
    const int mm = tid >> 5, lane = tid & 31;

    float M = -1e30f, S = 0.f;
    #pragma unroll 4
    for (int i = 0; i < 32; ++i) {
        const float v = logpy[mm * K_CB + i * 32 + lane];
        const float Mn = fmaxf(M, v);
        S = S * expf(M - Mn) + expf(v - Mn);
        M = Mn;
    }
    #pragma unroll
    for (int off = 16; off >= 1; off >>= 1) {
        const float Mb = __shfl_xor(M, off, 32);
        const float Sb = __shfl_xor(S, off, 32);
        const float Mn = fmaxf(M, Mb);
        S = S * expf(M - Mn) + Sb * expf(Mb - Mn);
        M = Mn;
    }
    if (lane == 0) lses[mm] = M + logf(S);

    float v = partial[tid] + partial[tid + 256] + partial[tid + 512] + partial[tid + 768];
    #pragma unroll
    for (int o = 32; o >= 1; o >>= 1) v += __shfl_xor(v, o, 64);
    if ((tid & 63) == 0) wred[tid >> 6] = v;
    __syncthreads();
    if (tid == 0) {
        const float ksum = wred[0] + wred[1] + wred[2] + wred[3];
        const float lsesum = lses[0] + lses[1] + lses[2] + lses[3]
                           + lses[4] + lses[5] + lses[6] + lses[7];
        out[(size_t)NB * M_CB * D_CB * HW]     = (ksum + 4096.f * lsesum) * 0.25f;
        out[(size_t)NB * M_CB * D_CB * HW + 1] = 0.f;
    }
}

extern "C" void kernel_launch(void* const* d_in, const int* in_sizes, int n_in,
                              void* d_out, int out_size, void* d_ws, size_t ws_size,
                              hipStream_t stream)
{
    const float* x      = (const float*)d_in[0];
    const float* mus    = (const float*)d_in[1];
    const float* scales = (const float*)d_in[2];
    const float* logpy  = (const float*)d_in[3];
    float* out = (float*)d_out;
    float* ws  = (float*)d_ws;

    float*  partial = ws + WS_PART;
    float*  A2l     = ws + WS_A;
    float*  c0l     = ws + WS_C0;
    ushort* wmu     = (ushort*)(ws + WS_MU_F);

    vq_convert<<<512,          256, 0, stream>>>(mus, scales, logpy, wmu, A2l, c0l);
    vq_main   <<<dim3(128, 8), 256, 0, stream>>>(x, wmu, mus, A2l, c0l, logpy, out, partial);
    vq_final  <<<1,            256, 0, stream>>>(logpy, partial, out);
}